// Round 5
// baseline (187.153 us; speedup 1.0000x reference)
//
#include <hip/hip_runtime.h>
#include <math.h>

// CrossAttentionModule: 3D neighborhood attention. All fp32.
// R5 = R4 + DIAGNOSTIC x4 in-kernel repetition of k_qkv and k_attn_proj
// bodies (idempotent; asm memory-clobber between reps prevents CSE).
// Purpose: surface per-kernel rocprof rows above the 44us harness fills.
// True per-kernel time = dur_us / 4.

#define PD 64
#define PH 64
#define PW 8
#define PTOT (PD*PH*PW)   // 32768
#define NC 64
#define NHEADS 8
#define HD 8
#define ATT_SCALE 0.35355339059327373f  // 1/sqrt(8)
#define DIAG_REP 4

// ws layout (floats)
#define WS_MR   0                      // 128 tc x {mean,rstd} = 256
#define WS_Q    1024
#define WS_K    (WS_Q + PTOT*NC)
#define WS_V    (WS_K + PTOT*NC)

__global__ __launch_bounds__(1024) void k_stats(const float* __restrict__ skip,
                                                const float* __restrict__ up,
                                                float* __restrict__ ws) {
  int tc = blockIdx.x;                // 0..127
  const float* src = (tc < 64) ? (skip + (size_t)tc * PTOT)
                               : (up + (size_t)(tc - 64) * PTOT);
  const float4* b4 = (const float4*)src;
  float s1 = 0.f, s2 = 0.f;
  #pragma unroll
  for (int it = 0; it < 8; it++) {
    float4 v = b4[it * 1024 + threadIdx.x];
    s1 += v.x + v.y + v.z + v.w;
    s2 += v.x*v.x + v.y*v.y + v.z*v.z + v.w*v.w;
  }
  #pragma unroll
  for (int off = 32; off; off >>= 1) {
    s1 += __shfl_down(s1, off);
    s2 += __shfl_down(s2, off);
  }
  __shared__ float red[32];
  int wid = threadIdx.x >> 6;
  if ((threadIdx.x & 63) == 0) { red[wid*2] = s1; red[wid*2+1] = s2; }
  __syncthreads();
  if (threadIdx.x == 0) {
    float a = 0.f, b = 0.f;
    #pragma unroll
    for (int w2 = 0; w2 < 16; w2++) { a += red[w2*2]; b += red[w2*2+1]; }
    float mean = a / (float)PTOT;
    float var  = b / (float)PTOT - mean*mean;
    ws[WS_MR + tc*2]     = mean;
    ws[WS_MR + tc*2 + 1] = rsqrtf(var + 1e-5f);
  }
}

// Fused inorm + QK/V projection (R2 structure), body repeated DIAG_REP times.
__global__ __launch_bounds__(256) void k_qkv(const float* __restrict__ skip,
                                             const float* __restrict__ up,
                                             const float* __restrict__ w_qk,
                                             const float* __restrict__ b_qk,
                                             const float* __restrict__ w_v,
                                             const float* __restrict__ b_v,
                                             float* __restrict__ ws) {
  int lane = threadIdx.x & 63;
  int wid  = threadIdx.x >> 6;
  int cs = __builtin_amdgcn_readfirstlane(blockIdx.y * 4 + wid);  // 0..11
  int p  = blockIdx.x * 64 + lane;
  const float* mr = ws + WS_MR;
  for (int rep = 0; rep < DIAG_REP; rep++) {
    float acc[16];
    if (cs < 8) {
      int jb = cs * 16;
      #pragma unroll
      for (int j = 0; j < 16; j++) acc[j] = b_qk[jb + j];
      const float* w = w_qk + jb;
      #pragma unroll 8
      for (int c = 0; c < NC; c++) {
        float a = (skip[(size_t)c * PTOT + p] - mr[c*2]) * mr[c*2+1];
        #pragma unroll
        for (int j = 0; j < 16; j++)
          acc[j] = fmaf(a, w[c*128 + j], acc[j]);
      }
      float* dst = ws + ((jb < 64) ? WS_Q : WS_K) + (size_t)p * NC + (jb & 63);
      #pragma unroll
      for (int g = 0; g < 4; g++)
        *(float4*)(dst + 4*g) = make_float4(acc[4*g], acc[4*g+1], acc[4*g+2], acc[4*g+3]);
    } else {
      int jb = (cs - 8) * 16;
      #pragma unroll
      for (int j = 0; j < 16; j++) acc[j] = b_v[jb + j];
      const float* w = w_v + jb;
      #pragma unroll 8
      for (int c = 0; c < NC; c++) {
        float a = (up[(size_t)c * PTOT + p] - mr[128 + c*2]) * mr[128 + c*2+1];
        #pragma unroll
        for (int j = 0; j < 16; j++)
          acc[j] = fmaf(a, w[c*64 + j], acc[j]);
      }
      float* dst = ws + WS_V + (size_t)p * NC + jb;
      #pragma unroll
      for (int g = 0; g < 4; g++)
        *(float4*)(dst + 4*g) = make_float4(acc[4*g], acc[4*g+1], acc[4*g+2], acc[4*g+3]);
    }
    asm volatile("" ::: "memory");   // prevent cross-rep CSE; reps stay observable
  }
}

// Fused attention + projection (R4 structure incl. XCD swizzle), body x4.
__global__ __launch_bounds__(512) void k_attn_proj(const float* __restrict__ rpb,
                                                   const float* __restrict__ w_proj,
                                                   const float* __restrict__ b_proj,
                                                   float* __restrict__ ws,
                                                   float* __restrict__ out) {
  __shared__ float A[64][65];
  __shared__ float rpb_s[NHEADS * 125];
  for (int i = threadIdx.x; i < NHEADS*125; i += 512) rpb_s[i] = rpb[i];
  __syncthreads();

  int bid = ((blockIdx.x & 7) << 6) + (blockIdx.x >> 3);   // XCD swizzle

  int wid  = threadIdx.x >> 6;
  int lane = threadIdx.x & 63;
  int job = bid * 8 + wid;
  int d = job >> 6;
  int h = job & 63;
  int w    = lane >> 3;
  int head = lane & 7;

  int sd = min(max(d - 1, 0), PD - 3);
  int sh = min(max(h - 1, 0), PH - 3);
  int sw = min(max(w - 1, 0), PW - 3);

  int pdre[3], phre[3], pwre[3], brd[3], brh[3], brw[3];
  #pragma unroll
  for (int j = 0; j < 3; j++) {
    pdre[j] = (sd + j) * (PH * PW);
    phre[j] = (sh + j) * PW;
    pwre[j] = sw + j;
    brd[j] = (sd + j - d + 2) * 25;
    brh[j] = (sh + j - h + 2) * 5;
    brw[j] = (sw + j - w + 2);
  }
  int p = (d * PH + h) * PW + w;
  const float* kb = ws + WS_K;
  const float* vb = ws + WS_V;
  int hb = head * 125;

  for (int rep = 0; rep < DIAG_REP; rep++) {
    const float* qb = ws + WS_Q + (size_t)p * NC + head * HD;
    float4 q0 = *(const float4*)qb;
    float4 q1 = *(const float4*)(qb + 4);

    float lg[27];
    float m = -1e30f;
    #pragma unroll
    for (int jd = 0; jd < 3; jd++)
    #pragma unroll
    for (int jh = 0; jh < 3; jh++)
    #pragma unroll
    for (int jw = 0; jw < 3; jw++) {
      int n = (jd * 3 + jh) * 3 + jw;
      int pn = pdre[jd] + phre[jh] + pwre[jw];
      const float4* kp = (const float4*)(kb + (size_t)pn * NC + head * HD);
      float4 k0 = kp[0], k1 = kp[1];
      float dot = q0.x*k0.x + q0.y*k0.y + q0.z*k0.z + q0.w*k0.w
                + q1.x*k1.x + q1.y*k1.y + q1.z*k1.z + q1.w*k1.w;
      float l = dot * ATT_SCALE + rpb_s[hb + brd[jd] + brh[jh] + brw[jw]];
      lg[n] = l;
      m = fmaxf(m, l);
    }
    float den = 0.f;
    #pragma unroll
    for (int n = 0; n < 27; n++) {
      float e = __expf(lg[n] - m);
      lg[n] = e;
      den += e;
    }
    float inv = 1.f / den;

    float4 a0 = make_float4(0,0,0,0), a1 = make_float4(0,0,0,0);
    #pragma unroll
    for (int jd = 0; jd < 3; jd++)
    #pragma unroll
    for (int jh = 0; jh < 3; jh++)
    #pragma unroll
    for (int jw = 0; jw < 3; jw++) {
      int n = (jd * 3 + jh) * 3 + jw;
      int pn = pdre[jd] + phre[jh] + pwre[jw];
      const float4* vp = (const float4*)(vb + (size_t)pn * NC + head * HD);
      float4 v0 = vp[0], v1 = vp[1];
      float wgt = lg[n];
      a0.x = fmaf(wgt, v0.x, a0.x); a0.y = fmaf(wgt, v0.y, a0.y);
      a0.z = fmaf(wgt, v0.z, a0.z); a0.w = fmaf(wgt, v0.w, a0.w);
      a1.x = fmaf(wgt, v1.x, a1.x); a1.y = fmaf(wgt, v1.y, a1.y);
      a1.z = fmaf(wgt, v1.z, a1.z); a1.w = fmaf(wgt, v1.w, a1.w);
    }
    int pl = wid * 8 + w;
    int cb = head * 8;
    A[pl][cb + 0] = a0.x * inv;
    A[pl][cb + 1] = a0.y * inv;
    A[pl][cb + 2] = a0.z * inv;
    A[pl][cb + 3] = a0.w * inv;
    A[pl][cb + 4] = a1.x * inv;
    A[pl][cb + 5] = a1.y * inv;
    A[pl][cb + 6] = a1.z * inv;
    A[pl][cb + 7] = a1.w * inv;
    __syncthreads();

    int jb = __builtin_amdgcn_readfirstlane(wid * 8);
    int p0 = bid * 64;
    float acc[8];
    #pragma unroll
    for (int j = 0; j < 8; j++) acc[j] = b_proj[jb + j];
    #pragma unroll 8
    for (int c = 0; c < NC; c++) {
      float a = A[lane][c];
      #pragma unroll
      for (int j = 0; j < 8; j++)
        acc[j] = fmaf(a, w_proj[c*64 + jb + j], acc[j]);
    }
    #pragma unroll
    for (int j = 0; j < 8; j++)
      out[(size_t)(jb + j) * PTOT + p0 + lane] = acc[j];
    __syncthreads();                 // protect A[] against next rep's writes
    asm volatile("" ::: "memory");   // keep each rep's loads/stores live
  }
}

extern "C" void kernel_launch(void* const* d_in, const int* in_sizes, int n_in,
                              void* d_out, int out_size, void* d_ws, size_t ws_size,
                              hipStream_t stream) {
  const float* skip = (const float*)d_in[0];
  const float* up   = (const float*)d_in[1];
  const float* w_qk = (const float*)d_in[2];
  const float* b_qk = (const float*)d_in[3];
  const float* w_v  = (const float*)d_in[4];
  const float* b_v  = (const float*)d_in[5];
  const float* w_pr = (const float*)d_in[6];
  const float* b_pr = (const float*)d_in[7];
  const float* rpb  = (const float*)d_in[8];
  float* ws  = (float*)d_ws;
  float* out = (float*)d_out;

  k_stats<<<128, 1024, 0, stream>>>(skip, up, ws);
  k_qkv<<<dim3(512, 3), 256, 0, stream>>>(skip, up, w_qk, b_qk, w_v, b_v, ws);
  k_attn_proj<<<(PD*PH)/8, 512, 0, stream>>>(rpb, w_pr, b_pr, ws, out);
}

// Round 6
// 66.517 us; speedup vs baseline: 2.8136x; 2.8136x over previous
//
#include <hip/hip_runtime.h>
#include <math.h>

// CrossAttentionModule: 3D neighborhood attention (NATTEN-style clamped window)
// B=1, C=64, D=64, H=64, W=8, HEADS=8, hd=8, K=(3,3,3), dil=1. All fp32.
//
// R6: k_attn_proj rebuilt for memory-level parallelism. R5 diagnostic showed
// ~670 cyc/load (serial L2 round-trips, ~1 load in flight). Neighbors are now
// processed in unrolled groups of 5: 10 independent dwordx4 loads issued into
// distinct registers before any consumer, for both the QK and PV passes.

#define PD 64
#define PH 64
#define PW 8
#define PTOT (PD*PH*PW)   // 32768
#define NC 64
#define NHEADS 8
#define HD 8
#define ATT_SCALE 0.35355339059327373f  // 1/sqrt(8)

// ws layout (floats)
#define WS_MR   0                      // 128 tc x {mean,rstd} = 256
#define WS_Q    1024
#define WS_K    (WS_Q + PTOT*NC)
#define WS_V    (WS_K + PTOT*NC)

__global__ __launch_bounds__(1024) void k_stats(const float* __restrict__ skip,
                                                const float* __restrict__ up,
                                                float* __restrict__ ws) {
  int tc = blockIdx.x;                // 0..127
  const float* src = (tc < 64) ? (skip + (size_t)tc * PTOT)
                               : (up + (size_t)(tc - 64) * PTOT);
  const float4* b4 = (const float4*)src;
  float s1 = 0.f, s2 = 0.f;
  #pragma unroll
  for (int it = 0; it < 8; it++) {
    float4 v = b4[it * 1024 + threadIdx.x];
    s1 += v.x + v.y + v.z + v.w;
    s2 += v.x*v.x + v.y*v.y + v.z*v.z + v.w*v.w;
  }
  #pragma unroll
  for (int off = 32; off; off >>= 1) {
    s1 += __shfl_down(s1, off);
    s2 += __shfl_down(s2, off);
  }
  __shared__ float red[32];
  int wid = threadIdx.x >> 6;
  if ((threadIdx.x & 63) == 0) { red[wid*2] = s1; red[wid*2+1] = s2; }
  __syncthreads();
  if (threadIdx.x == 0) {
    float a = 0.f, b = 0.f;
    #pragma unroll
    for (int w2 = 0; w2 < 16; w2++) { a += red[w2*2]; b += red[w2*2+1]; }
    float mean = a / (float)PTOT;
    float var  = b / (float)PTOT - mean*mean;   // population var (ddof=0)
    ws[WS_MR + tc*2]     = mean;
    ws[WS_MR + tc*2 + 1] = rsqrtf(var + 1e-5f);
  }
}

// Fused inorm + QK/V projection (unchanged control from R2).
__global__ __launch_bounds__(256) void k_qkv(const float* __restrict__ skip,
                                             const float* __restrict__ up,
                                             const float* __restrict__ w_qk,
                                             const float* __restrict__ b_qk,
                                             const float* __restrict__ w_v,
                                             const float* __restrict__ b_v,
                                             float* __restrict__ ws) {
  int lane = threadIdx.x & 63;
  int wid  = threadIdx.x >> 6;
  int cs = __builtin_amdgcn_readfirstlane(blockIdx.y * 4 + wid);  // 0..11
  int p  = blockIdx.x * 64 + lane;
  const float* mr = ws + WS_MR;
  float acc[16];
  if (cs < 8) {
    int jb = cs * 16;
    #pragma unroll
    for (int j = 0; j < 16; j++) acc[j] = b_qk[jb + j];
    const float* w = w_qk + jb;
    #pragma unroll 8
    for (int c = 0; c < NC; c++) {
      float a = (skip[(size_t)c * PTOT + p] - mr[c*2]) * mr[c*2+1];
      #pragma unroll
      for (int j = 0; j < 16; j++)
        acc[j] = fmaf(a, w[c*128 + j], acc[j]);
    }
    float* dst = ws + ((jb < 64) ? WS_Q : WS_K) + (size_t)p * NC + (jb & 63);
    #pragma unroll
    for (int g = 0; g < 4; g++)
      *(float4*)(dst + 4*g) = make_float4(acc[4*g], acc[4*g+1], acc[4*g+2], acc[4*g+3]);
  } else {
    int jb = (cs - 8) * 16;
    #pragma unroll
    for (int j = 0; j < 16; j++) acc[j] = b_v[jb + j];
    const float* w = w_v + jb;
    #pragma unroll 8
    for (int c = 0; c < NC; c++) {
      float a = (up[(size_t)c * PTOT + p] - mr[128 + c*2]) * mr[128 + c*2+1];
      #pragma unroll
      for (int j = 0; j < 16; j++)
        acc[j] = fmaf(a, w[c*64 + j], acc[j]);
    }
    float* dst = ws + WS_V + (size_t)p * NC + jb;
    #pragma unroll
    for (int g = 0; g < 4; g++)
      *(float4*)(dst + 4*g) = make_float4(acc[4*g], acc[4*g+1], acc[4*g+2], acc[4*g+3]);
  }
}

// Fused attention + output projection with grouped-prefetch loads.
// Block = 512 threads = 8 waves = 8 consecutive (d,h) rows. Per lane (w,head):
// 27-neighbor attention; K/V loads issued 10-at-a-time into distinct regs.
__global__ __launch_bounds__(512) void k_attn_proj(const float* __restrict__ rpb,
                                                   const float* __restrict__ w_proj,
                                                   const float* __restrict__ b_proj,
                                                   float* __restrict__ ws,
                                                   float* __restrict__ out) {
  __shared__ float A[64][65];
  __shared__ float rpb_s[NHEADS * 125];
  for (int i = threadIdx.x; i < NHEADS*125; i += 512) rpb_s[i] = rpb[i];
  __syncthreads();

  int bid = ((blockIdx.x & 7) << 6) + (blockIdx.x >> 3);   // XCD swizzle

  int wid  = threadIdx.x >> 6;
  int lane = threadIdx.x & 63;
  int job = bid * 8 + wid;
  int d = job >> 6;
  int h = job & 63;
  int w    = lane >> 3;
  int head = lane & 7;

  int sd = min(max(d - 1, 0), PD - 3);
  int sh = min(max(h - 1, 0), PH - 3);
  int sw = min(max(w - 1, 0), PW - 3);

  int pdre[3], phre[3], pwre[3], brd[3], brh[3], brw[3];
  #pragma unroll
  for (int j = 0; j < 3; j++) {
    pdre[j] = (sd + j) * (PH * PW);
    phre[j] = (sh + j) * PW;
    pwre[j] = sw + j;
    brd[j] = (sd + j - d + 2) * 25;
    brh[j] = (sh + j - h + 2) * 5;
    brw[j] = (sw + j - w + 2);
  }
  int p = (d * PH + h) * PW + w;

  const float* qb = ws + WS_Q + (size_t)p * NC + head * HD;
  float4 q0 = *(const float4*)qb;
  float4 q1 = *(const float4*)(qb + 4);
  const float* kb = ws + WS_K + head * HD;
  const float* vb = ws + WS_V + head * HD;
  int hb = head * 125;

  // neighbor n -> (jd,jh,jw), all compile-time after unroll
  #define NJD(n) ((n) / 9)
  #define NJH(n) (((n) / 3) % 3)
  #define NJW(n) ((n) % 3)

  float lg[27];
  float m = -1e30f;
  // QK pass: groups of 5 neighbors, 10 independent dwordx4 loads per group.
  #pragma unroll
  for (int g0 = 0; g0 < 27; g0 += 5) {
    float4 ka[10];
    #pragma unroll
    for (int i = 0; i < 5; i++) {
      int n = g0 + i;
      if (n < 27) {
        int pn = pdre[NJD(n)] + phre[NJH(n)] + pwre[NJW(n)];
        const float4* kp = (const float4*)(kb + (size_t)pn * NC);
        ka[2*i]   = kp[0];
        ka[2*i+1] = kp[1];
      }
    }
    #pragma unroll
    for (int i = 0; i < 5; i++) {
      int n = g0 + i;
      if (n < 27) {
        float4 k0 = ka[2*i], k1 = ka[2*i+1];
        float dot = q0.x*k0.x + q0.y*k0.y + q0.z*k0.z + q0.w*k0.w
                  + q1.x*k1.x + q1.y*k1.y + q1.z*k1.z + q1.w*k1.w;
        float l = dot * ATT_SCALE
                + rpb_s[hb + brd[NJD(n)] + brh[NJH(n)] + brw[NJW(n)]];
        lg[n] = l;
        m = fmaxf(m, l);
      }
    }
  }
  float den = 0.f;
  #pragma unroll
  for (int n = 0; n < 27; n++) {
    float e = __expf(lg[n] - m);
    lg[n] = e;
    den += e;
  }
  float inv = 1.f / den;

  // PV pass: same grouped prefetch on V.
  float4 a0 = make_float4(0,0,0,0), a1 = make_float4(0,0,0,0);
  #pragma unroll
  for (int g0 = 0; g0 < 27; g0 += 5) {
    float4 va[10];
    #pragma unroll
    for (int i = 0; i < 5; i++) {
      int n = g0 + i;
      if (n < 27) {
        int pn = pdre[NJD(n)] + phre[NJH(n)] + pwre[NJW(n)];
        const float4* vp = (const float4*)(vb + (size_t)pn * NC);
        va[2*i]   = vp[0];
        va[2*i+1] = vp[1];
      }
    }
    #pragma unroll
    for (int i = 0; i < 5; i++) {
      int n = g0 + i;
      if (n < 27) {
        float4 v0 = va[2*i], v1 = va[2*i+1];
        float wgt = lg[n];
        a0.x = fmaf(wgt, v0.x, a0.x); a0.y = fmaf(wgt, v0.y, a0.y);
        a0.z = fmaf(wgt, v0.z, a0.z); a0.w = fmaf(wgt, v0.w, a0.w);
        a1.x = fmaf(wgt, v1.x, a1.x); a1.y = fmaf(wgt, v1.y, a1.y);
        a1.z = fmaf(wgt, v1.z, a1.z); a1.w = fmaf(wgt, v1.w, a1.w);
      }
    }
  }
  int pl = wid * 8 + w;                // position within block (0..63)
  int cb = head * 8;                   // channel base for this lane
  A[pl][cb + 0] = a0.x * inv;
  A[pl][cb + 1] = a0.y * inv;
  A[pl][cb + 2] = a0.z * inv;
  A[pl][cb + 3] = a0.w * inv;
  A[pl][cb + 4] = a1.x * inv;
  A[pl][cb + 5] = a1.y * inv;
  A[pl][cb + 6] = a1.z * inv;
  A[pl][cb + 7] = a1.w * inv;
  __syncthreads();

  // Phase 2: projection. Wave wid handles columns jb..jb+7 for all 64 pos.
  int jb = __builtin_amdgcn_readfirstlane(wid * 8);
  int p0 = bid * 64;
  float acc[8];
  #pragma unroll
  for (int j = 0; j < 8; j++) acc[j] = b_proj[jb + j];
  #pragma unroll 8
  for (int c = 0; c < NC; c++) {
    float a = A[lane][c];              // stride 65: conflict-free
    #pragma unroll
    for (int j = 0; j < 8; j++)
      acc[j] = fmaf(a, w_proj[c*64 + jb + j], acc[j]);
  }
  #pragma unroll
  for (int j = 0; j < 8; j++)
    out[(size_t)(jb + j) * PTOT + p0 + lane] = acc[j];
}

extern "C" void kernel_launch(void* const* d_in, const int* in_sizes, int n_in,
                              void* d_out, int out_size, void* d_ws, size_t ws_size,
                              hipStream_t stream) {
  const float* skip = (const float*)d_in[0];
  const float* up   = (const float*)d_in[1];
  const float* w_qk = (const float*)d_in[2];
  const float* b_qk = (const float*)d_in[3];
  const float* w_v  = (const float*)d_in[4];
  const float* b_v  = (const float*)d_in[5];
  const float* w_pr = (const float*)d_in[6];
  const float* b_pr = (const float*)d_in[7];
  const float* rpb  = (const float*)d_in[8];
  float* ws  = (float*)d_ws;
  float* out = (float*)d_out;

  k_stats<<<128, 1024, 0, stream>>>(skip, up, ws);
  k_qkv<<<dim3(512, 3), 256, 0, stream>>>(skip, up, w_qk, b_qk, w_v, b_v, ws);
  k_attn_proj<<<(PD*PH)/8, 512, 0, stream>>>(rpb, w_pr, b_pr, ws, out);
}